// Round 8
// baseline (882.239 us; speedup 1.0000x reference)
//
#include <hip/hip_runtime.h>
#include <hip/hip_bf16.h>

// ---------------------------------------------------------------------------
// Types / helpers
// ---------------------------------------------------------------------------
typedef __bf16 bf16x8 __attribute__((ext_vector_type(8)));
typedef float f32x16 __attribute__((ext_vector_type(16)));

// fp32 -> bf16 bits, round-to-nearest-even (inputs are finite; no NaN path)
__device__ __forceinline__ unsigned short f2bs(float f) {
    unsigned u = __builtin_bit_cast(unsigned, f);
    u = (u + 0x7fffu + ((u >> 16) & 1u)) >> 16;
    return (unsigned short)u;
}
__device__ __forceinline__ float bs2f(unsigned short s) {
    unsigned u = ((unsigned)s) << 16;
    return __builtin_bit_cast(float, u);
}

#define GLDS16(gp, lp)                                                        \
    __builtin_amdgcn_global_load_lds(                                         \
        (const __attribute__((address_space(1))) void*)(gp),                  \
        (__attribute__((address_space(3))) void*)(lp), 16, 0, 0)

#define TCHUNK 32

// ---------------------------------------------------------------------------
// Kernel 1a: per-chunk sums + write the h-half of X in bf16.
// ---------------------------------------------------------------------------
__global__ __launch_bounds__(256) void feats_partial(
    const float* __restrict__ h, float* __restrict__ partial,
    unsigned short* __restrict__ X, int B, int T, int D, int nC) {
    const int d = blockIdx.z * 256 + threadIdx.x;
    const int b = blockIdx.x, c = blockIdx.y;
    const int t0 = c * TCHUNK;
    const int t1 = min(t0 + TCHUNK, T);
    const float* hp = h + ((long)b * T + t0) * D + d;
    unsigned short* xp = X + ((long)b * T + t0) * (2 * D) + D + d;
    float s = 0.f;
    for (int t = t0; t < t1; ++t) {
        float v = *hp;
        *xp = f2bs(v);
        s += v;
        hp += D;
        xp += 2 * D;
    }
    partial[((long)b * nC + c) * D + d] = s;
}

// ---------------------------------------------------------------------------
// Kernel 1b: write the prefix-mean half (reads bf16 h-half back).
// ---------------------------------------------------------------------------
__global__ __launch_bounds__(256) void feats_write(
    const float* __restrict__ partial, unsigned short* __restrict__ X,
    int B, int T, int D, int nC) {
    const int d = blockIdx.z * 256 + threadIdx.x;
    const int b = blockIdx.x, c = blockIdx.y;
    const int t0 = c * TCHUNK;
    const int t1 = min(t0 + TCHUNK, T);
    float sum = 0.f;
    for (int cc = 0; cc < c; ++cc)
        sum += partial[((long)b * nC + cc) * D + d];
    unsigned short* xp = X + ((long)b * T + t0) * (2 * D) + d;
    for (int t = t0; t < t1; ++t) {
        float pm = (t == 0) ? 0.f : sum / (float)t;
        xp[0] = f2bs(pm);
        sum += bs2f(xp[D]);
        xp += 2 * D;
    }
}

// ---------------------------------------------------------------------------
// Kernel 2: transpose + cast. W: [K][N] fp32 -> WT: [N][K] bf16 bits.
// ---------------------------------------------------------------------------
__global__ __launch_bounds__(256) void transpose_cast(
    const float* __restrict__ W, unsigned short* __restrict__ WT,
    int K, int N) {
    __shared__ float tile[32][33];
    const int n0 = blockIdx.x * 32, k0 = blockIdx.y * 32;
    const int tx = threadIdx.x, ty = threadIdx.y;
    #pragma unroll
    for (int i = ty; i < 32; i += 8)
        tile[i][tx] = W[(long)(k0 + i) * N + n0 + tx];
    __syncthreads();
    #pragma unroll
    for (int i = ty; i < 32; i += 8)
        WT[(long)(n0 + i) * K + k0 + tx] = f2bs(tile[tx][i]);
}

// ---------------------------------------------------------------------------
// Kernel 2b: out[m] = b3 (init for the fused-head atomics)
// ---------------------------------------------------------------------------
__global__ __launch_bounds__(256) void init_out(
    float* __restrict__ out, const float* __restrict__ b3, int M) {
    int m = blockIdx.x * 256 + threadIdx.x;
    if (m < M) out[m] = b3[0];
}

// ---------------------------------------------------------------------------
// Kernel 3: GEMM  C[M,N] = relu(A[M,K] * BT[N,K]^T + bias)
// R8: tile 256x128 (was 128x128). 4 waves stacked vertically; wave w owns
// rows [w*64, w*64+64) x ALL 128 cols, acc[2][4] (128 acc VGPRs).
// WHY: R7 counters show latency-bound (LDS busy 21%, MFMA 29%, rest =
// per-iter vmcnt(0)+barrier drain ~2700cyc/block-iter). Doubling FLOPs per
// staged k-iter halves the latency cost per FLOP; LDS-read:MFMA ratio
// improves 1:1 -> 1.33:1. 24KB LDS/block.
// Kept: 32x32x16 MFMA, XOR bank swizzle (R7: frag conflicts 7.5e7->2.5e7
// floor), supertile XCD map (R5), global_load_lds(16).
// LESSONS (do not re-try): R4 min-waves bound -> acc spills -> 5x slower.
// Watch VGPR: <=170 -> 3 waves/EU; spill -> revert.
// ---------------------------------------------------------------------------
template <int NCOL, bool FUSE>
__global__ __launch_bounds__(256) void gemm_bt_bias_relu(
    const unsigned short* __restrict__ A,   // [M,K] bf16 bits
    const unsigned short* __restrict__ BT,  // [N,K] bf16 bits
    const float* __restrict__ bias,         // [N]
    unsigned short* __restrict__ C,         // [M,N] bf16 bits (unused if FUSE)
    const float* __restrict__ W3,           // [N] head weights (FUSE only)
    float* __restrict__ outp,               // [M] (FUSE only)
    int M, int N, int K) {
    __shared__ __align__(16) unsigned short As[256 * 32];
    __shared__ __align__(16) unsigned short Bs[128 * 32];

    const int tid = threadIdx.x;
    const int lane = tid & 63;
    const int wave = tid >> 6;
    const int wm = wave * 64;      // wave's row offset within the 256-row tile
    const int l31 = lane & 31;
    const int half = lane >> 5;

    // ---- supertile block mapping (all scalar; SS=8, perSup is pow2) ----
    const int SS = 8;
    const int nRow = M >> 8;               // 256-row panels
    const int perSup = SS * NCOL;
    const int nFull = nRow / SS;
    const int fullBlocks = nFull * perSup;
    const int blk = blockIdx.x;
    int row_blk, col_blk;
    if (blk < fullBlocks) {
        const int sup = blk / perSup;
        const int w = blk % perSup;
        row_blk = sup * SS + (w & (SS - 1));
        col_blk = w >> 3;
    } else {
        const int rem = blk - fullBlocks;
        const int rt = nRow - nFull * SS;
        row_blk = nFull * SS + rem % rt;
        col_blk = rem / rt;
    }

    const long row0 = (long)row_blk * 256;
    const long col0 = (long)col_blk * 128;

    const unsigned short* Ab = A + row0 * K;
    const unsigned short* Bb = BT + col0 * K;

    const int sr = tid >> 2;                              // staging row 0..63
    const int sc = (((tid & 3) ^ ((tid >> 3) & 3)) * 8);  // swizzled source col

    f32x16 acc[2][4];
    #pragma unroll
    for (int i = 0; i < 2; ++i)
        #pragma unroll
        for (int j = 0; j < 4; ++j)
            acc[i][j] = (f32x16)(0.f);

    // fragment-read swizzle offsets (row-periodic mod 8; wm%32==0 safe)
    const int e0 = ((half ^ ((l31 >> 1) & 3)) * 8);
    const int e1 = e0 ^ 16;

    const unsigned short* pa0 = As + (wm + l31) * 32;
    const unsigned short* pa1 = pa0 + 32 * 32;
    const unsigned short* pb0 = Bs + l31 * 32;

    for (int kt = 0; kt < K; kt += 32) {
        // stage A 256x32 (4 chunks) + B 128x32 (2 chunks)
        GLDS16(Ab + (long)sr * K + kt + sc,          As + tid * 8);
        GLDS16(Ab + (long)(sr + 64) * K + kt + sc,   As + (256 + tid) * 8);
        GLDS16(Ab + (long)(sr + 128) * K + kt + sc,  As + (512 + tid) * 8);
        GLDS16(Ab + (long)(sr + 192) * K + kt + sc,  As + (768 + tid) * 8);
        GLDS16(Bb + (long)sr * K + kt + sc,          Bs + tid * 8);
        GLDS16(Bb + (long)(sr + 64) * K + kt + sc,   Bs + (256 + tid) * 8);
        __syncthreads();

        #pragma unroll
        for (int kk = 0; kk < 2; ++kk) {
            const int e = kk ? e1 : e0;
            bf16x8 a0 = *(const bf16x8*)(pa0 + e);
            bf16x8 a1 = *(const bf16x8*)(pa1 + e);
            bf16x8 b0 = *(const bf16x8*)(pb0 + e);
            bf16x8 b1 = *(const bf16x8*)(pb0 + 32 * 32 + e);
            bf16x8 b2 = *(const bf16x8*)(pb0 + 64 * 32 + e);
            bf16x8 b3v = *(const bf16x8*)(pb0 + 96 * 32 + e);
            acc[0][0] = __builtin_amdgcn_mfma_f32_32x32x16_bf16(a0, b0,  acc[0][0], 0, 0, 0);
            acc[0][1] = __builtin_amdgcn_mfma_f32_32x32x16_bf16(a0, b1,  acc[0][1], 0, 0, 0);
            acc[0][2] = __builtin_amdgcn_mfma_f32_32x32x16_bf16(a0, b2,  acc[0][2], 0, 0, 0);
            acc[0][3] = __builtin_amdgcn_mfma_f32_32x32x16_bf16(a0, b3v, acc[0][3], 0, 0, 0);
            acc[1][0] = __builtin_amdgcn_mfma_f32_32x32x16_bf16(a1, b0,  acc[1][0], 0, 0, 0);
            acc[1][1] = __builtin_amdgcn_mfma_f32_32x32x16_bf16(a1, b1,  acc[1][1], 0, 0, 0);
            acc[1][2] = __builtin_amdgcn_mfma_f32_32x32x16_bf16(a1, b2,  acc[1][2], 0, 0, 0);
            acc[1][3] = __builtin_amdgcn_mfma_f32_32x32x16_bf16(a1, b3v, acc[1][3], 0, 0, 0);
        }

        __syncthreads();
    }

    // Epilogue. C/D: col=lane&31, row=(reg&3)+8*(reg>>2)+4*half (m74/m101)
    if (!FUSE) {
        float bv[4];
        #pragma unroll
        for (int jt = 0; jt < 4; ++jt)
            bv[jt] = bias[col0 + jt * 32 + l31];
        #pragma unroll
        for (int it = 0; it < 2; ++it) {
            #pragma unroll
            for (int reg = 0; reg < 16; ++reg) {
                const long row =
                    row0 + wm + it * 32 + (reg & 3) + 8 * (reg >> 2) + 4 * half;
                #pragma unroll
                for (int jt = 0; jt < 4; ++jt) {
                    const long col = col0 + jt * 32 + l31;
                    float v = fmaxf(acc[it][jt][reg] + bv[jt], 0.f);
                    C[row * N + col] = f2bs(v);
                }
            }
        }
    } else {
        float w3v[4], bv[4];
        #pragma unroll
        for (int jt = 0; jt < 4; ++jt) {
            const long col = col0 + jt * 32 + l31;
            w3v[jt] = W3[col];
            bv[jt] = bias[col];
        }
        #pragma unroll
        for (int it = 0; it < 2; ++it) {
            #pragma unroll
            for (int reg = 0; reg < 16; ++reg) {
                float s = 0.f;
                #pragma unroll
                for (int jt = 0; jt < 4; ++jt)
                    s += fmaxf(acc[it][jt][reg] + bv[jt], 0.f) * w3v[jt];
                s += __shfl_xor(s, 1, 64);
                s += __shfl_xor(s, 2, 64);
                s += __shfl_xor(s, 4, 64);
                s += __shfl_xor(s, 8, 64);
                s += __shfl_xor(s, 16, 64);
                if (l31 == 0) {
                    const long row = row0 + wm + it * 32 + (reg & 3) +
                                     8 * (reg >> 2) + 4 * half;
                    atomicAdd(&outp[row], s);
                }
            }
        }
    }
}

// ---------------------------------------------------------------------------
// Launch
// ---------------------------------------------------------------------------
extern "C" void kernel_launch(void* const* d_in, const int* in_sizes, int n_in,
                              void* d_out, int out_size, void* d_ws,
                              size_t ws_size, hipStream_t stream) {
    const float* h  = (const float*)d_in[0];
    const float* W1 = (const float*)d_in[1];
    const float* b1 = (const float*)d_in[2];
    const float* W2 = (const float*)d_in[3];
    const float* b2 = (const float*)d_in[4];
    const float* W3 = (const float*)d_in[5];
    const float* b3 = (const float*)d_in[6];
    float* out = (float*)d_out;

    const int B = 128, T = 254, D = 768, H = 1024;
    const int M = B * T;        // 32512 = 127 * 256
    const int K1 = 2 * D;       // 1536
    const int N1 = 2 * H;       // 2048
    const int K2 = N1;          // 2048
    const int N2 = H;           // 1024
    const int nC = (T + TCHUNK - 1) / TCHUNK;  // 8

    char* ws = (char*)d_ws;
    size_t off = 0;
    auto alloc = [&](size_t bytes) {
        char* p = ws + off;
        off += (bytes + 255) & ~(size_t)255;
        return p;
    };
    unsigned short* X   = (unsigned short*)alloc((size_t)M * K1 * 2);  // 99.9 MB
    unsigned short* H1  = (unsigned short*)alloc((size_t)M * N1 * 2);  // 133.2 MB
    unsigned short* W1T = (unsigned short*)alloc((size_t)N1 * K1 * 2); // 6.3 MB
    unsigned short* W2T = (unsigned short*)alloc((size_t)N2 * K2 * 2); // 4.2 MB
    float* partial      = (float*)alloc((size_t)B * nC * D * 4);       // 3.1 MB

    dim3 tb(32, 8);
    transpose_cast<<<dim3(N1 / 32, K1 / 32), tb, 0, stream>>>(W1, W1T, K1, N1);
    transpose_cast<<<dim3(N2 / 32, K2 / 32), tb, 0, stream>>>(W2, W2T, K2, N2);

    feats_partial<<<dim3(B, nC, D / 256), 256, 0, stream>>>(
        h, partial, X, B, T, D, nC);
    feats_write<<<dim3(B, nC, D / 256), 256, 0, stream>>>(
        partial, X, B, T, D, nC);

    init_out<<<dim3((M + 255) / 256), 256, 0, stream>>>(out, b3, M);

    // 1D grid with device-side supertile mapping; 256-row tiles
    gemm_bt_bias_relu<16, false><<<dim3((M / 256) * (N1 / 128)), 256, 0, stream>>>(
        X, W1T, b1, H1, nullptr, nullptr, M, N1, K1);
    gemm_bt_bias_relu<8, true><<<dim3((M / 256) * (N2 / 128)), 256, 0, stream>>>(
        H1, W2T, b2, nullptr, W3, out, M, N2, K2);
}

// Round 9
// 612.571 us; speedup vs baseline: 1.4402x; 1.4402x over previous
//
#include <hip/hip_runtime.h>
#include <hip/hip_bf16.h>

// ---------------------------------------------------------------------------
// Types / helpers
// ---------------------------------------------------------------------------
typedef __bf16 bf16x8 __attribute__((ext_vector_type(8)));
typedef float f32x16 __attribute__((ext_vector_type(16)));

// fp32 -> bf16 bits, round-to-nearest-even (inputs are finite; no NaN path)
__device__ __forceinline__ unsigned short f2bs(float f) {
    unsigned u = __builtin_bit_cast(unsigned, f);
    u = (u + 0x7fffu + ((u >> 16) & 1u)) >> 16;
    return (unsigned short)u;
}
__device__ __forceinline__ float bs2f(unsigned short s) {
    unsigned u = ((unsigned)s) << 16;
    return __builtin_bit_cast(float, u);
}

#define GLDS16(gp, lp)                                                        \
    __builtin_amdgcn_global_load_lds(                                         \
        (const __attribute__((address_space(1))) void*)(gp),                  \
        (__attribute__((address_space(3))) void*)(lp), 16, 0, 0)

#define TCHUNK 32

// ---------------------------------------------------------------------------
// Kernel 1a: per-chunk sums + write the h-half of X in bf16.
// ---------------------------------------------------------------------------
__global__ __launch_bounds__(256) void feats_partial(
    const float* __restrict__ h, float* __restrict__ partial,
    unsigned short* __restrict__ X, int B, int T, int D, int nC) {
    const int d = blockIdx.z * 256 + threadIdx.x;
    const int b = blockIdx.x, c = blockIdx.y;
    const int t0 = c * TCHUNK;
    const int t1 = min(t0 + TCHUNK, T);
    const float* hp = h + ((long)b * T + t0) * D + d;
    unsigned short* xp = X + ((long)b * T + t0) * (2 * D) + D + d;
    float s = 0.f;
    for (int t = t0; t < t1; ++t) {
        float v = *hp;
        *xp = f2bs(v);
        s += v;
        hp += D;
        xp += 2 * D;
    }
    partial[((long)b * nC + c) * D + d] = s;
}

// ---------------------------------------------------------------------------
// Kernel 1b: write the prefix-mean half (reads bf16 h-half back).
// ---------------------------------------------------------------------------
__global__ __launch_bounds__(256) void feats_write(
    const float* __restrict__ partial, unsigned short* __restrict__ X,
    int B, int T, int D, int nC) {
    const int d = blockIdx.z * 256 + threadIdx.x;
    const int b = blockIdx.x, c = blockIdx.y;
    const int t0 = c * TCHUNK;
    const int t1 = min(t0 + TCHUNK, T);
    float sum = 0.f;
    for (int cc = 0; cc < c; ++cc)
        sum += partial[((long)b * nC + cc) * D + d];
    unsigned short* xp = X + ((long)b * T + t0) * (2 * D) + d;
    for (int t = t0; t < t1; ++t) {
        float pm = (t == 0) ? 0.f : sum / (float)t;
        xp[0] = f2bs(pm);
        sum += bs2f(xp[D]);
        xp += 2 * D;
    }
}

// ---------------------------------------------------------------------------
// Kernel 2: transpose + cast. W: [K][N] fp32 -> WT: [N][K] bf16 bits.
// ---------------------------------------------------------------------------
__global__ __launch_bounds__(256) void transpose_cast(
    const float* __restrict__ W, unsigned short* __restrict__ WT,
    int K, int N) {
    __shared__ float tile[32][33];
    const int n0 = blockIdx.x * 32, k0 = blockIdx.y * 32;
    const int tx = threadIdx.x, ty = threadIdx.y;
    #pragma unroll
    for (int i = ty; i < 32; i += 8)
        tile[i][tx] = W[(long)(k0 + i) * N + n0 + tx];
    __syncthreads();
    #pragma unroll
    for (int i = ty; i < 32; i += 8)
        WT[(long)(n0 + i) * K + k0 + tx] = f2bs(tile[tx][i]);
}

// ---------------------------------------------------------------------------
// Kernel 2b: out[m] = b3 (init for the fused-head atomics)
// ---------------------------------------------------------------------------
__global__ __launch_bounds__(256) void init_out(
    float* __restrict__ out, const float* __restrict__ b3, int M) {
    int m = blockIdx.x * 256 + threadIdx.x;
    if (m < M) out[m] = b3[0];
}

// ---------------------------------------------------------------------------
// Kernel 3: GEMM  C[M,N] = relu(A[M,K] * BT[N,K]^T + bias)
// R9: 128x128 tile, BK=64 (was 32). Halves iteration/barrier count while
// keeping acc[2][2] = 64 AGPRs.
// REGISTER MODEL (R8 lesson): VGPR_Count = ARCH regs only; AGPR acc is on
// top (unified pool). Occupancy = 512/(arch+acc). R7: 80+64=144 -> 3
// waves/EU. R8's 256-row tile: 144+128=272 -> 1 wave/EU -> 412us. Never
// exceed 64 acc regs; keep arch <= ~105.
// Swizzle (row = 64 elems = 8 chunks): chunk c of row r at slot c^(r&7);
// staging source col = ((tid&7)^((tid>>3)&7))*8; fragment offset
// ((kk*2+half)^(l31&7))*8 -> all 8 b128 bank groups hit evenly, every read.
// Kept: 32x32x16 MFMA (R6), supertile XCD map (R5), global_load_lds(16).
// LESSONS: R4 min-waves bound -> acc spills -> 5x. No min-waves arg.
// FUSE: head layer folded into epilogue (shuffle-reduce + atomicAdd).
// ---------------------------------------------------------------------------
template <int NCOL, bool FUSE>
__global__ __launch_bounds__(256) void gemm_bt_bias_relu(
    const unsigned short* __restrict__ A,   // [M,K] bf16 bits
    const unsigned short* __restrict__ BT,  // [N,K] bf16 bits
    const float* __restrict__ bias,         // [N]
    unsigned short* __restrict__ C,         // [M,N] bf16 bits (unused if FUSE)
    const float* __restrict__ W3,           // [N] head weights (FUSE only)
    float* __restrict__ outp,               // [M] (FUSE only)
    int M, int N, int K) {
    __shared__ __align__(16) unsigned short As[128 * 64];
    __shared__ __align__(16) unsigned short Bs[128 * 64];

    const int tid = threadIdx.x;
    const int lane = tid & 63;
    const int wave = tid >> 6;
    const int wm = (wave >> 1) * 64;
    const int wn = (wave & 1) * 64;
    const int l31 = lane & 31;
    const int half = lane >> 5;

    // ---- supertile block mapping (all scalar; SS=8, perSup is pow2) ----
    const int SS = 8;
    const int nRow = M >> 7;
    const int perSup = SS * NCOL;
    const int nFull = nRow / SS;
    const int fullBlocks = nFull * perSup;
    const int blk = blockIdx.x;
    int row_blk, col_blk;
    if (blk < fullBlocks) {
        const int sup = blk / perSup;
        const int w = blk % perSup;
        row_blk = sup * SS + (w & (SS - 1));
        col_blk = w >> 3;
    } else {
        const int rem = blk - fullBlocks;
        const int rt = nRow - nFull * SS;
        row_blk = nFull * SS + rem % rt;
        col_blk = rem / rt;
    }

    const long row0 = (long)row_blk * 128;
    const long col0 = (long)col_blk * 128;

    const unsigned short* Ab = A + row0 * K;
    const unsigned short* Bb = BT + col0 * K;

    const int sr = tid >> 3;                              // staging row 0..31
    const int sc = (((tid & 7) ^ ((tid >> 3) & 7)) * 8);  // swizzled source col

    f32x16 acc[2][2];
    #pragma unroll
    for (int i = 0; i < 2; ++i)
        #pragma unroll
        for (int j = 0; j < 2; ++j)
            acc[i][j] = (f32x16)(0.f);

    const int esw = l31 & 7;   // row-dependent part of the read swizzle

    const unsigned short* pa0 = As + (wm + l31) * 64;
    const unsigned short* pa1 = pa0 + 32 * 64;
    const unsigned short* pb0 = Bs + (wn + l31) * 64;
    const unsigned short* pb1 = pb0 + 32 * 64;

    for (int kt = 0; kt < K; kt += 64) {
        // stage A 128x64 and B 128x64, 4 chunks each per thread
        #pragma unroll
        for (int i = 0; i < 4; ++i)
            GLDS16(Ab + (long)(sr + i * 32) * K + kt + sc,
                   As + (i * 256 + tid) * 8);
        #pragma unroll
        for (int i = 0; i < 4; ++i)
            GLDS16(Bb + (long)(sr + i * 32) * K + kt + sc,
                   Bs + (i * 256 + tid) * 8);
        __syncthreads();

        #pragma unroll
        for (int kk = 0; kk < 4; ++kk) {
            const int e = (((kk * 2 + half) ^ esw) * 8);
            bf16x8 a0 = *(const bf16x8*)(pa0 + e);
            bf16x8 a1 = *(const bf16x8*)(pa1 + e);
            bf16x8 b0 = *(const bf16x8*)(pb0 + e);
            bf16x8 b1 = *(const bf16x8*)(pb1 + e);
            acc[0][0] = __builtin_amdgcn_mfma_f32_32x32x16_bf16(a0, b0, acc[0][0], 0, 0, 0);
            acc[0][1] = __builtin_amdgcn_mfma_f32_32x32x16_bf16(a0, b1, acc[0][1], 0, 0, 0);
            acc[1][0] = __builtin_amdgcn_mfma_f32_32x32x16_bf16(a1, b0, acc[1][0], 0, 0, 0);
            acc[1][1] = __builtin_amdgcn_mfma_f32_32x32x16_bf16(a1, b1, acc[1][1], 0, 0, 0);
        }

        __syncthreads();
    }

    // Epilogue. C/D: col=lane&31, row=(reg&3)+8*(reg>>2)+4*half (m74/m101)
    if (!FUSE) {
        float bv[2];
        #pragma unroll
        for (int jt = 0; jt < 2; ++jt)
            bv[jt] = bias[col0 + wn + jt * 32 + l31];
        #pragma unroll
        for (int it = 0; it < 2; ++it) {
            #pragma unroll
            for (int reg = 0; reg < 16; ++reg) {
                const long row =
                    row0 + wm + it * 32 + (reg & 3) + 8 * (reg >> 2) + 4 * half;
                #pragma unroll
                for (int jt = 0; jt < 2; ++jt) {
                    const long col = col0 + wn + jt * 32 + l31;
                    float v = fmaxf(acc[it][jt][reg] + bv[jt], 0.f);
                    C[row * N + col] = f2bs(v);
                }
            }
        }
    } else {
        float w3v[2], bv[2];
        #pragma unroll
        for (int jt = 0; jt < 2; ++jt) {
            const long col = col0 + wn + jt * 32 + l31;
            w3v[jt] = W3[col];
            bv[jt] = bias[col];
        }
        #pragma unroll
        for (int it = 0; it < 2; ++it) {
            #pragma unroll
            for (int reg = 0; reg < 16; ++reg) {
                float s = 0.f;
                #pragma unroll
                for (int jt = 0; jt < 2; ++jt)
                    s += fmaxf(acc[it][jt][reg] + bv[jt], 0.f) * w3v[jt];
                s += __shfl_xor(s, 1, 64);
                s += __shfl_xor(s, 2, 64);
                s += __shfl_xor(s, 4, 64);
                s += __shfl_xor(s, 8, 64);
                s += __shfl_xor(s, 16, 64);
                if (l31 == 0) {
                    const long row = row0 + wm + it * 32 + (reg & 3) +
                                     8 * (reg >> 2) + 4 * half;
                    atomicAdd(&outp[row], s);
                }
            }
        }
    }
}

// ---------------------------------------------------------------------------
// Launch
// ---------------------------------------------------------------------------
extern "C" void kernel_launch(void* const* d_in, const int* in_sizes, int n_in,
                              void* d_out, int out_size, void* d_ws,
                              size_t ws_size, hipStream_t stream) {
    const float* h  = (const float*)d_in[0];
    const float* W1 = (const float*)d_in[1];
    const float* b1 = (const float*)d_in[2];
    const float* W2 = (const float*)d_in[3];
    const float* b2 = (const float*)d_in[4];
    const float* W3 = (const float*)d_in[5];
    const float* b3 = (const float*)d_in[6];
    float* out = (float*)d_out;

    const int B = 128, T = 254, D = 768, H = 1024;
    const int M = B * T;        // 32512
    const int K1 = 2 * D;       // 1536
    const int N1 = 2 * H;       // 2048
    const int K2 = N1;          // 2048
    const int N2 = H;           // 1024
    const int nC = (T + TCHUNK - 1) / TCHUNK;  // 8

    char* ws = (char*)d_ws;
    size_t off = 0;
    auto alloc = [&](size_t bytes) {
        char* p = ws + off;
        off += (bytes + 255) & ~(size_t)255;
        return p;
    };
    unsigned short* X   = (unsigned short*)alloc((size_t)M * K1 * 2);  // 99.9 MB
    unsigned short* H1  = (unsigned short*)alloc((size_t)M * N1 * 2);  // 133.2 MB
    unsigned short* W1T = (unsigned short*)alloc((size_t)N1 * K1 * 2); // 6.3 MB
    unsigned short* W2T = (unsigned short*)alloc((size_t)N2 * K2 * 2); // 4.2 MB
    float* partial      = (float*)alloc((size_t)B * nC * D * 4);       // 3.1 MB

    dim3 tb(32, 8);
    transpose_cast<<<dim3(N1 / 32, K1 / 32), tb, 0, stream>>>(W1, W1T, K1, N1);
    transpose_cast<<<dim3(N2 / 32, K2 / 32), tb, 0, stream>>>(W2, W2T, K2, N2);

    feats_partial<<<dim3(B, nC, D / 256), 256, 0, stream>>>(
        h, partial, X, B, T, D, nC);
    feats_write<<<dim3(B, nC, D / 256), 256, 0, stream>>>(
        partial, X, B, T, D, nC);

    init_out<<<dim3((M + 255) / 256), 256, 0, stream>>>(out, b3, M);

    // 1D grid with device-side supertile mapping; 128x128 tiles
    gemm_bt_bias_relu<16, false><<<dim3((M / 128) * (N1 / 128)), 256, 0, stream>>>(
        X, W1T, b1, H1, nullptr, nullptr, M, N1, K1);
    gemm_bt_bias_relu<8, true><<<dim3((M / 128) * (N2 / 128)), 256, 0, stream>>>(
        H1, W2T, b2, nullptr, W3, out, M, N2, K2);
}